// Round 5
// baseline (202.520 us; speedup 1.0000x reference)
//
#include <hip/hip_runtime.h>

#define N_NODES 10000
#define N_EDGES 640000
#define ELL_W   128    // max in-degree capacity; Poisson(64) => P(deg>127) ~ 1e-14
#define NB      157    // buckets of 64 nodes: bucket = dst >> 6 (10000/64 = 156.25)
#define BCAP    4600   // per-bucket capacity (mean 4076, +8 sigma)
#define LCAP    80     // per-wg per-bucket LDS bin capacity (mean 15.9, huge margin)
#define CHUNK   2500   // edges per workgroup in phase 1 (256 wgs * 2500 = 640000)

typedef short short8 __attribute__((ext_vector_type(8)));
typedef float f32x4 __attribute__((ext_vector_type(4)));

__device__ inline float bf2f(unsigned short u) {
    return __uint_as_float(((unsigned)u) << 16);
}
// round-to-nearest-even f32 -> bf16 (data here is never NaN)
__device__ inline unsigned short f2bf(float f) {
    unsigned u = __float_as_uint(f);
    u += 0x7fffu + ((u >> 16) & 1u);
    return (unsigned short)(u >> 16);
}

// ---------------------------------------------------------------------------
// Tiny zero kernel for bucket cursors (replaces pathological hipMemsetAsync)
// ---------------------------------------------------------------------------
__global__ __launch_bounds__(256) void zero_cursor(int* __restrict__ g) {
    if (threadIdx.x < NB) g[threadIdx.x] = 0;
}

// ---------------------------------------------------------------------------
// Phase 1: bin edges by dst bucket (dst>>6) via LDS, coalesced flush.
// Packed word: (src << 6) | (dst & 63)   (src < 16384 -> fits)
// ---------------------------------------------------------------------------
__global__ __launch_bounds__(256) void bin_edges(const int* __restrict__ src,
                                                 const int* __restrict__ dst,
                                                 int* __restrict__ gCursor,
                                                 unsigned* __restrict__ gBucket) {
    __shared__ unsigned bins[NB][LCAP];
    __shared__ int cnt[NB];
    __shared__ int base[NB];
    int t = threadIdx.x;
    for (int i = t; i < NB; i += 256) cnt[i] = 0;
    __syncthreads();

    int e0 = blockIdx.x * CHUNK;
    int e1 = min(e0 + CHUNK, N_EDGES);
    for (int e = e0 + t; e < e1; e += 256) {
        int d = dst[e];
        int b = d >> 6;
        unsigned pk = ((unsigned)src[e] << 6) | (unsigned)(d & 63);
        int p = atomicAdd(&cnt[b], 1);
        if (p < LCAP) bins[b][p] = pk;
    }
    __syncthreads();
    for (int i = t; i < NB; i += 256) {
        int c = min(cnt[i], LCAP);
        cnt[i] = c;
        base[i] = atomicAdd(&gCursor[i], c);
    }
    __syncthreads();
    for (int b = 0; b < NB; ++b) {
        int ba = base[b];
        int n = min(cnt[b], max(0, BCAP - ba));
        for (int i = t; i < n; i += 256)
            gBucket[(size_t)b * BCAP + ba + i] = bins[b][i];
    }
}

// ---------------------------------------------------------------------------
// Phase 2: one workgroup per bucket; build 64 ELL rows in LDS, write coalesced.
// No global atomics; every ELL cache line written by exactly one CU.
// ---------------------------------------------------------------------------
__global__ __launch_bounds__(256) void build_ell(const unsigned* __restrict__ gBucket,
                                                 const int* __restrict__ gCursor,
                                                 unsigned short* __restrict__ ell,
                                                 int* __restrict__ deg) {
    __shared__ unsigned short rows[64 * ELL_W];  // 16 KB
    __shared__ int ldeg[64];
    int b = blockIdx.x;
    int t = threadIdx.x;
    for (int i = t; i < 64; i += 256) ldeg[i] = 0;
    __syncthreads();

    int n = min(gCursor[b], BCAP);
    const unsigned* bk = gBucket + (size_t)b * BCAP;
    for (int i = t; i < n; i += 256) {
        unsigned pk = bk[i];
        int local = pk & 63;
        int s = pk >> 6;
        int p = atomicAdd(&ldeg[local], 1);
        if (p < ELL_W) rows[local * ELL_W + p] = (unsigned short)s;
    }
    __syncthreads();

    int node0 = b * 64;
    int nNodes = min(64, N_NODES - node0);
    if (nNodes <= 0) return;
    for (int i = t; i < nNodes; i += 256)
        deg[node0 + i] = min(ldeg[i], ELL_W);
    // coalesced 16B writes of the row image (garbage beyond deg is never read)
    int totalVec = nNodes * (ELL_W / 8);
    short8* dstv = (short8*)(ell + (size_t)node0 * ELL_W);
    const short8* srcv = (const short8*)rows;
    for (int i = t; i < totalVec; i += 256) dstv[i] = srcv[i];
}

// ---------------------------------------------------------------------------
// Conversions: x fp32 -> bf16; weights fp32 [K][N] -> bf16 transposed [N][K]
// ---------------------------------------------------------------------------
__global__ __launch_bounds__(256) void cvt_x_kernel(const float4* __restrict__ x,
                                                    ushort4* __restrict__ xb, int n4) {
    int i = blockIdx.x * 256 + threadIdx.x;
    if (i >= n4) return;
    float4 v = x[i];
    ushort4 o;
    o.x = f2bf(v.x); o.y = f2bf(v.y); o.z = f2bf(v.z); o.w = f2bf(v.w);
    xb[i] = o;
}

struct WList {
    const float* src[6];
    unsigned short* dst[6];
    int K[6];
    int off[7];  // element offsets, N == 256 for all
};

__global__ __launch_bounds__(256) void cvt_w_kernel(WList wl, int total) {
    int idx = blockIdx.x * 256 + threadIdx.x;
    if (idx >= total) return;
    int w = 0;
    while (idx >= wl.off[w + 1]) ++w;
    int r = idx - wl.off[w];
    int k = r >> 8;          // N = 256
    int n = r & 255;
    wl.dst[w][(size_t)n * wl.K[w] + k] = f2bf(wl.src[w][r]);
}

// ---------------------------------------------------------------------------
// Gather aggregation (bf16, fp32 accumulate), 128 channels per dispatch so the
// random-row working set (2.56 MB) stays L2-resident per XCD. `half` selects
// the channel half (separate serial dispatches, not blockIdx.y).
// ---------------------------------------------------------------------------
template <int U2STRIDE>
__global__ __launch_bounds__(256) void gather_ell(const unsigned* __restrict__ x,
                                                  const unsigned short* __restrict__ ell,
                                                  const int* __restrict__ deg,
                                                  unsigned* __restrict__ out, int half) {
    int wid = (blockIdx.x * 256 + threadIdx.x) >> 6;  // node id
    int lane = threadIdx.x & 63;
    if (wid >= N_NODES) return;
    int off = half * 64 + lane;  // uint offset within row

    unsigned v = x[(size_t)wid * U2STRIDE + off];
    float a0 = bf2f((unsigned short)(v & 0xffff));
    float a1 = bf2f((unsigned short)(v >> 16));

    int dg = min(deg[wid], ELL_W);
    const unsigned short* row = ell + (size_t)wid * ELL_W;

    int j = 0;
    for (; j + 8 <= dg; j += 8) {
        ushort4 sA = *(const ushort4*)(row + j);
        ushort4 sB = *(const ushort4*)(row + j + 4);
        unsigned v0 = x[(size_t)sA.x * U2STRIDE + off];
        unsigned v1 = x[(size_t)sA.y * U2STRIDE + off];
        unsigned v2 = x[(size_t)sA.z * U2STRIDE + off];
        unsigned v3 = x[(size_t)sA.w * U2STRIDE + off];
        unsigned v4 = x[(size_t)sB.x * U2STRIDE + off];
        unsigned v5 = x[(size_t)sB.y * U2STRIDE + off];
        unsigned v6 = x[(size_t)sB.z * U2STRIDE + off];
        unsigned v7 = x[(size_t)sB.w * U2STRIDE + off];
        a0 += (bf2f((unsigned short)(v0 & 0xffff)) + bf2f((unsigned short)(v1 & 0xffff))) +
              (bf2f((unsigned short)(v2 & 0xffff)) + bf2f((unsigned short)(v3 & 0xffff))) +
              (bf2f((unsigned short)(v4 & 0xffff)) + bf2f((unsigned short)(v5 & 0xffff))) +
              (bf2f((unsigned short)(v6 & 0xffff)) + bf2f((unsigned short)(v7 & 0xffff)));
        a1 += (bf2f((unsigned short)(v0 >> 16)) + bf2f((unsigned short)(v1 >> 16))) +
              (bf2f((unsigned short)(v2 >> 16)) + bf2f((unsigned short)(v3 >> 16))) +
              (bf2f((unsigned short)(v4 >> 16)) + bf2f((unsigned short)(v5 >> 16))) +
              (bf2f((unsigned short)(v6 >> 16)) + bf2f((unsigned short)(v7 >> 16)));
    }
    for (; j < dg; ++j) {
        unsigned vv = x[(size_t)row[j] * U2STRIDE + off];
        a0 += bf2f((unsigned short)(vv & 0xffff));
        a1 += bf2f((unsigned short)(vv >> 16));
    }
    unsigned o = (unsigned)f2bf(a0) | ((unsigned)f2bf(a1) << 16);
    out[(size_t)wid * U2STRIDE + off] = o;
}

// ---------------------------------------------------------------------------
// Fused MLP: out = (ReLU(A @ WA + bA)) @ WB + bB  [+ReLU2] — one dispatch.
// Block = 256 thr = 4 waves; 32 output rows per block; wave w owns col quarter
// w*64..w*64+63 in BOTH stages. Hidden (32x256 bf16) staged in LDS, pitch 264
// (+8 pad -> conflict-free b128 reads). Wt layouts are [N][K] bf16.
// MFMA fragment mapping (mfma_f32_16x16x32_bf16, HW-verified):
//   A: row = lane&15, k = (lane>>4)*8 + j ; B: col = lane&15, same k
//   D: col = lane&15, row = (lane>>4)*4 + reg
// ---------------------------------------------------------------------------
template <int KSTEPS, bool RELU2, bool F32OUT>
__global__ __launch_bounds__(256) void mlp_mfma(const unsigned short* __restrict__ A,
                                                const unsigned short* __restrict__ WtA,
                                                const float* __restrict__ biasA,
                                                const unsigned short* __restrict__ WtB,
                                                const float* __restrict__ biasB,
                                                void* __restrict__ Cout) {
    constexpr int K1 = KSTEPS * 32;
    constexpr int LP = 264;  // LDS pitch in bf16 elems (528 B = 33*16, b128-aligned)
    __shared__ unsigned short hid[32 * LP];  // 16.5 KB

    int r0 = blockIdx.x * 32;
    int tid = threadIdx.x;
    int lane = tid & 63;
    int nq = tid >> 6;      // wave id = column quarter
    int lrow = lane & 15;
    int lkg = lane >> 4;
    int n0 = nq * 64;

    // ---- stage 1: hidden = ReLU(A @ WA + bA)
    {
        const short8* Ap0 = (const short8*)(A + (size_t)(r0 + lrow) * K1 + lkg * 8);
        const short8* Ap1 = (const short8*)(A + (size_t)(r0 + 16 + lrow) * K1 + lkg * 8);
        const short8* Bp = (const short8*)(WtA + (size_t)(n0 + lrow) * K1 + lkg * 8);
        f32x4 acc[2][4] = {};
#pragma unroll
        for (int ks = 0; ks < KSTEPS; ++ks) {
            short8 a0 = Ap0[ks * 4];
            short8 a1 = Ap1[ks * 4];
            short8 b0 = Bp[ks * 4 + 0 * 2 * K1];
            short8 b1 = Bp[ks * 4 + 1 * 2 * K1];
            short8 b2 = Bp[ks * 4 + 2 * 2 * K1];
            short8 b3 = Bp[ks * 4 + 3 * 2 * K1];
            acc[0][0] = __builtin_amdgcn_mfma_f32_16x16x32_bf16(a0, b0, acc[0][0], 0, 0, 0);
            acc[0][1] = __builtin_amdgcn_mfma_f32_16x16x32_bf16(a0, b1, acc[0][1], 0, 0, 0);
            acc[0][2] = __builtin_amdgcn_mfma_f32_16x16x32_bf16(a0, b2, acc[0][2], 0, 0, 0);
            acc[0][3] = __builtin_amdgcn_mfma_f32_16x16x32_bf16(a0, b3, acc[0][3], 0, 0, 0);
            acc[1][0] = __builtin_amdgcn_mfma_f32_16x16x32_bf16(a1, b0, acc[1][0], 0, 0, 0);
            acc[1][1] = __builtin_amdgcn_mfma_f32_16x16x32_bf16(a1, b1, acc[1][1], 0, 0, 0);
            acc[1][2] = __builtin_amdgcn_mfma_f32_16x16x32_bf16(a1, b2, acc[1][2], 0, 0, 0);
            acc[1][3] = __builtin_amdgcn_mfma_f32_16x16x32_bf16(a1, b3, acc[1][3], 0, 0, 0);
        }
#pragma unroll
        for (int rg = 0; rg < 2; ++rg) {
            int row = rg * 16 + lkg * 4;
#pragma unroll
            for (int nt = 0; nt < 4; ++nt) {
                int c = n0 + nt * 16 + lrow;
                float bv = biasA[c];
#pragma unroll
                for (int r = 0; r < 4; ++r) {
                    float v = fmaxf(acc[rg][nt][r] + bv, 0.f);
                    hid[(row + r) * LP + c] = f2bf(v);
                }
            }
        }
    }
    __syncthreads();

    // ---- stage 2: out = hidden @ WB + bB
    {
        const short8* Bp = (const short8*)(WtB + (size_t)(n0 + lrow) * 256 + lkg * 8);
        f32x4 acc[2][4] = {};
#pragma unroll
        for (int ks = 0; ks < 8; ++ks) {
            short8 a0 = *(const short8*)&hid[lrow * LP + ks * 32 + lkg * 8];
            short8 a1 = *(const short8*)&hid[(16 + lrow) * LP + ks * 32 + lkg * 8];
            short8 b0 = Bp[ks * 4 + 0 * 2 * 256];
            short8 b1 = Bp[ks * 4 + 1 * 2 * 256];
            short8 b2 = Bp[ks * 4 + 2 * 2 * 256];
            short8 b3 = Bp[ks * 4 + 3 * 2 * 256];
            acc[0][0] = __builtin_amdgcn_mfma_f32_16x16x32_bf16(a0, b0, acc[0][0], 0, 0, 0);
            acc[0][1] = __builtin_amdgcn_mfma_f32_16x16x32_bf16(a0, b1, acc[0][1], 0, 0, 0);
            acc[0][2] = __builtin_amdgcn_mfma_f32_16x16x32_bf16(a0, b2, acc[0][2], 0, 0, 0);
            acc[0][3] = __builtin_amdgcn_mfma_f32_16x16x32_bf16(a0, b3, acc[0][3], 0, 0, 0);
            acc[1][0] = __builtin_amdgcn_mfma_f32_16x16x32_bf16(a1, b0, acc[1][0], 0, 0, 0);
            acc[1][1] = __builtin_amdgcn_mfma_f32_16x16x32_bf16(a1, b1, acc[1][1], 0, 0, 0);
            acc[1][2] = __builtin_amdgcn_mfma_f32_16x16x32_bf16(a1, b2, acc[1][2], 0, 0, 0);
            acc[1][3] = __builtin_amdgcn_mfma_f32_16x16x32_bf16(a1, b3, acc[1][3], 0, 0, 0);
        }
#pragma unroll
        for (int rg = 0; rg < 2; ++rg) {
            int orow = r0 + rg * 16 + lkg * 4;
#pragma unroll
            for (int nt = 0; nt < 4; ++nt) {
                int c = n0 + nt * 16 + lrow;
                float bv = biasB[c];
#pragma unroll
                for (int r = 0; r < 4; ++r) {
                    int grow = orow + r;
                    if (grow >= N_NODES) continue;
                    float v = acc[rg][nt][r] + bv;
                    if (RELU2) v = fmaxf(v, 0.f);
                    if (F32OUT)
                        ((float*)Cout)[(size_t)grow * 256 + c] = v;
                    else
                        ((unsigned short*)Cout)[(size_t)grow * 256 + c] = f2bf(v);
                }
            }
        }
    }
}

// ---------------------------------------------------------------------------
extern "C" void kernel_launch(void* const* d_in, const int* in_sizes, int n_in,
                              void* d_out, int out_size, void* d_ws, size_t ws_size,
                              hipStream_t stream) {
    const float* x   = (const float*)d_in[0];
    const int*   ei  = (const int*)d_in[1];
    const int*   src = ei;
    const int*   dst = ei + N_EDGES;
    const float* W0a = (const float*)d_in[2];
    const float* b0a = (const float*)d_in[3];
    const float* W0b = (const float*)d_in[4];
    const float* b0b = (const float*)d_in[5];
    const float* W1a = (const float*)d_in[6];
    const float* b1a = (const float*)d_in[7];
    const float* W1b = (const float*)d_in[8];
    const float* b1b = (const float*)d_in[9];
    const float* W2a = (const float*)d_in[10];
    const float* b2a = (const float*)d_in[11];
    const float* W2b = (const float*)d_in[12];
    const float* b2b = (const float*)d_in[13];

    char* ws = (char*)d_ws;
    size_t off = 0;
    auto alloc = [&](size_t bytes) {
        void* p = ws + off;
        off += (bytes + 255) & ~(size_t)255;
        return p;
    };
    unsigned short* xb    = (unsigned short*)alloc((size_t)N_NODES * 128 * 2);
    unsigned short* B0    = (unsigned short*)alloc((size_t)N_NODES * 256 * 2);
    unsigned short* B2    = (unsigned short*)alloc((size_t)N_NODES * 256 * 2);
    unsigned short* Wt0a  = (unsigned short*)alloc(256 * 128 * 2);
    unsigned short* Wt0b  = (unsigned short*)alloc(256 * 256 * 2);
    unsigned short* Wt1a  = (unsigned short*)alloc(256 * 256 * 2);
    unsigned short* Wt1b  = (unsigned short*)alloc(256 * 256 * 2);
    unsigned short* Wt2a  = (unsigned short*)alloc(256 * 256 * 2);
    unsigned short* Wt2b  = (unsigned short*)alloc(256 * 256 * 2);
    int*            deg   = (int*)alloc(N_NODES * 4);
    unsigned short* ell   = (unsigned short*)alloc((size_t)N_NODES * ELL_W * 2);
    int*            gCur  = (int*)alloc(NB * 4);
    unsigned*       gBkt  = (unsigned*)alloc((size_t)NB * BCAP * 4);

    int gatherBlocks = (N_NODES + 3) / 4;       // 2500 (4 waves/block)
    int mlpBlocks = (N_NODES + 31) / 32;        // 313

    // ---- ELL build: zero cursors -> bin -> build (no global atomic scatter) ----
    zero_cursor<<<1, 256, 0, stream>>>(gCur);
    bin_edges<<<(N_EDGES + CHUNK - 1) / CHUNK, 256, 0, stream>>>(src, dst, gCur, gBkt);
    build_ell<<<NB, 256, 0, stream>>>(gBkt, gCur, ell, deg);

    // ---- Precision conversion ----
    cvt_x_kernel<<<(N_NODES * 128 / 4 + 255) / 256, 256, 0, stream>>>(
        (const float4*)x, (ushort4*)xb, N_NODES * 128 / 4);
    WList wl;
    wl.src[0] = W0a; wl.dst[0] = Wt0a; wl.K[0] = 128;
    wl.src[1] = W0b; wl.dst[1] = Wt0b; wl.K[1] = 256;
    wl.src[2] = W1a; wl.dst[2] = Wt1a; wl.K[2] = 256;
    wl.src[3] = W1b; wl.dst[3] = Wt1b; wl.K[3] = 256;
    wl.src[4] = W2a; wl.dst[4] = Wt2a; wl.K[4] = 256;
    wl.src[5] = W2b; wl.dst[5] = Wt2b; wl.K[5] = 256;
    int total = 0;
    for (int i = 0; i < 6; ++i) { wl.off[i] = total; total += wl.K[i] * 256; }
    wl.off[6] = total;
    cvt_w_kernel<<<(total + 255) / 256, 256, 0, stream>>>(wl, total);

    // ---- Layer 0 (C_in = 128) ----
    gather_ell<64><<<gatherBlocks, 256, 0, stream>>>((const unsigned*)xb, ell, deg, (unsigned*)B0, 0);
    mlp_mfma<4, true, false><<<mlpBlocks, 256, 0, stream>>>(B0, Wt0a, b0a, Wt0b, b0b, B2);
    // ---- Layer 1 (C = 256) ----
    gather_ell<128><<<gatherBlocks, 256, 0, stream>>>((const unsigned*)B2, ell, deg, (unsigned*)B0, 0);
    gather_ell<128><<<gatherBlocks, 256, 0, stream>>>((const unsigned*)B2, ell, deg, (unsigned*)B0, 1);
    mlp_mfma<8, true, false><<<mlpBlocks, 256, 0, stream>>>(B0, Wt1a, b1a, Wt1b, b1b, B2);
    // ---- Layer 2 (C = 256, final out fp32, no ReLU) ----
    gather_ell<128><<<gatherBlocks, 256, 0, stream>>>((const unsigned*)B2, ell, deg, (unsigned*)B0, 0);
    gather_ell<128><<<gatherBlocks, 256, 0, stream>>>((const unsigned*)B2, ell, deg, (unsigned*)B0, 1);
    mlp_mfma<8, false, true><<<mlpBlocks, 256, 0, stream>>>(B0, Wt2a, b2a, Wt2b, b2b, d_out);
}

// Round 6
// 179.246 us; speedup vs baseline: 1.1298x; 1.1298x over previous
//
#include <hip/hip_runtime.h>

#define N_NODES 10000
#define N_EDGES 640000
#define ELL_W   128    // max in-degree capacity; Poisson(64) => P(deg>127) ~ 1e-14
#define NB      157    // buckets of 64 nodes: bucket = dst >> 6
#define BCAP    4600   // per-bucket capacity (mean 4076, +8 sigma)
#define LCAP    80     // per-wg per-bucket LDS bin capacity (mean ~16, +16 sigma)
#define CHUNK   2500   // edges per workgroup in phase 1 (256 wgs * 2500 = 640000)

typedef short short8 __attribute__((ext_vector_type(8)));
typedef float f32x4 __attribute__((ext_vector_type(4)));

__device__ inline float bf2f(unsigned short u) {
    return __uint_as_float(((unsigned)u) << 16);
}
// round-to-nearest-even f32 -> bf16 (data here is never NaN)
__device__ inline unsigned short f2bf(float f) {
    unsigned u = __float_as_uint(f);
    u += 0x7fffu + ((u >> 16) & 1u);
    return (unsigned short)(u >> 16);
}

// ---------------------------------------------------------------------------
// Tiny zero kernel for bucket cursors (hipMemsetAsync's runtime kernel was 43us)
// ---------------------------------------------------------------------------
__global__ __launch_bounds__(256) void zero_cursor(int* __restrict__ g) {
    if (threadIdx.x < NB) g[threadIdx.x] = 0;
}

// ---------------------------------------------------------------------------
// Phase 1: bin edges by dst bucket (dst>>6) via LDS, coalesced flush.
// Packed word: (src << 6) | (dst & 63). Flush is wave-parallel over buckets.
// ---------------------------------------------------------------------------
__global__ __launch_bounds__(256) void bin_edges(const int* __restrict__ src,
                                                 const int* __restrict__ dst,
                                                 int* __restrict__ gCursor,
                                                 unsigned* __restrict__ gBucket) {
    __shared__ unsigned bins[NB][LCAP];
    __shared__ int cnt[NB];
    __shared__ int base[NB];
    int t = threadIdx.x;
    for (int i = t; i < NB; i += 256) cnt[i] = 0;
    __syncthreads();

    int e0 = blockIdx.x * CHUNK;
    int e1 = min(e0 + CHUNK, N_EDGES);
    for (int e = e0 + t; e < e1; e += 256) {
        int d = dst[e];
        int b = d >> 6;
        unsigned pk = ((unsigned)src[e] << 6) | (unsigned)(d & 63);
        int p = atomicAdd(&cnt[b], 1);
        if (p < LCAP) bins[b][p] = pk;
    }
    __syncthreads();
    for (int i = t; i < NB; i += 256) {
        int c = min(cnt[i], LCAP);
        cnt[i] = c;
        base[i] = atomicAdd(&gCursor[i], c);
    }
    __syncthreads();
    int wave = t >> 6, lane = t & 63;
    for (int b = wave; b < NB; b += 4) {
        int ba = base[b];
        int n = min(cnt[b], max(0, BCAP - ba));
        for (int i = lane; i < n; i += 64)
            gBucket[(size_t)b * BCAP + ba + i] = bins[b][i];
    }
}

// ---------------------------------------------------------------------------
// Phase 2: one workgroup per bucket; build 64 ELL rows in LDS, write coalesced.
// No global atomics; every ELL cache line written by exactly one CU.
// ---------------------------------------------------------------------------
__global__ __launch_bounds__(256) void build_ell(const unsigned* __restrict__ gBucket,
                                                 const int* __restrict__ gCursor,
                                                 unsigned short* __restrict__ ell,
                                                 int* __restrict__ deg) {
    __shared__ unsigned short rows[64 * ELL_W];  // 16 KB
    __shared__ int ldeg[64];
    int b = blockIdx.x;
    int t = threadIdx.x;
    for (int i = t; i < 64; i += 256) ldeg[i] = 0;
    __syncthreads();

    int n = min(gCursor[b], BCAP);
    const unsigned* bk = gBucket + (size_t)b * BCAP;
    for (int i = t; i < n; i += 256) {
        unsigned pk = bk[i];
        int local = pk & 63;
        int s = pk >> 6;
        int p = atomicAdd(&ldeg[local], 1);
        if (p < ELL_W) rows[local * ELL_W + p] = (unsigned short)s;
    }
    __syncthreads();

    int node0 = b * 64;
    int nNodes = min(64, N_NODES - node0);
    if (nNodes <= 0) return;
    for (int i = t; i < nNodes; i += 256)
        deg[node0 + i] = min(ldeg[i], ELL_W);
    // coalesced 16B writes of the row image (garbage beyond deg is never read)
    int totalVec = nNodes * (ELL_W / 8);
    short8* dstv = (short8*)(ell + (size_t)node0 * ELL_W);
    const short8* srcv = (const short8*)rows;
    for (int i = t; i < totalVec; i += 256) dstv[i] = srcv[i];
}

// ---------------------------------------------------------------------------
// Conversions: x fp32 -> bf16; weights fp32 [K][N] -> bf16 transposed [N][K]
// ---------------------------------------------------------------------------
__global__ __launch_bounds__(256) void cvt_x_kernel(const float4* __restrict__ x,
                                                    ushort4* __restrict__ xb, int n4) {
    int i = blockIdx.x * 256 + threadIdx.x;
    if (i >= n4) return;
    float4 v = x[i];
    ushort4 o;
    o.x = f2bf(v.x); o.y = f2bf(v.y); o.z = f2bf(v.z); o.w = f2bf(v.w);
    xb[i] = o;
}

struct WList {
    const float* src[6];
    unsigned short* dst[6];
    int K[6];
    int off[7];  // element offsets, N == 256 for all
};

__global__ __launch_bounds__(256) void cvt_w_kernel(WList wl, int total) {
    int idx = blockIdx.x * 256 + threadIdx.x;
    if (idx >= total) return;
    int w = 0;
    while (idx >= wl.off[w + 1]) ++w;
    int r = idx - wl.off[w];
    int k = r >> 8;          // N = 256
    int n = r & 255;
    wl.dst[w][(size_t)n * wl.K[w] + k] = f2bf(wl.src[w][r]);
}

// ---------------------------------------------------------------------------
// Gather aggregation (bf16, fp32 accumulate), 128 channels per wave-pass so the
// random-row working set (2.56 MB) stays mostly L2-resident per XCD.
// One wave per (node, half). U2STRIDE = uints per row (C/2). blockIdx.y = half.
// ---------------------------------------------------------------------------
template <int U2STRIDE>
__global__ __launch_bounds__(256) void gather_ell(const unsigned* __restrict__ x,
                                                  const unsigned short* __restrict__ ell,
                                                  const int* __restrict__ deg,
                                                  unsigned* __restrict__ out) {
    int wid = (blockIdx.x * 256 + threadIdx.x) >> 6;  // node id
    int lane = threadIdx.x & 63;
    if (wid >= N_NODES) return;
    int off = blockIdx.y * 64 + lane;  // uint offset within row

    unsigned v = x[(size_t)wid * U2STRIDE + off];
    float a0 = bf2f((unsigned short)(v & 0xffff));
    float a1 = bf2f((unsigned short)(v >> 16));

    int dg = min(deg[wid], ELL_W);
    const unsigned short* row = ell + (size_t)wid * ELL_W;

    int j = 0;
    for (; j + 8 <= dg; j += 8) {
        ushort4 sA = *(const ushort4*)(row + j);
        ushort4 sB = *(const ushort4*)(row + j + 4);
        unsigned v0 = x[(size_t)sA.x * U2STRIDE + off];
        unsigned v1 = x[(size_t)sA.y * U2STRIDE + off];
        unsigned v2 = x[(size_t)sA.z * U2STRIDE + off];
        unsigned v3 = x[(size_t)sA.w * U2STRIDE + off];
        unsigned v4 = x[(size_t)sB.x * U2STRIDE + off];
        unsigned v5 = x[(size_t)sB.y * U2STRIDE + off];
        unsigned v6 = x[(size_t)sB.z * U2STRIDE + off];
        unsigned v7 = x[(size_t)sB.w * U2STRIDE + off];
        a0 += (bf2f((unsigned short)(v0 & 0xffff)) + bf2f((unsigned short)(v1 & 0xffff))) +
              (bf2f((unsigned short)(v2 & 0xffff)) + bf2f((unsigned short)(v3 & 0xffff))) +
              (bf2f((unsigned short)(v4 & 0xffff)) + bf2f((unsigned short)(v5 & 0xffff))) +
              (bf2f((unsigned short)(v6 & 0xffff)) + bf2f((unsigned short)(v7 & 0xffff)));
        a1 += (bf2f((unsigned short)(v0 >> 16)) + bf2f((unsigned short)(v1 >> 16))) +
              (bf2f((unsigned short)(v2 >> 16)) + bf2f((unsigned short)(v3 >> 16))) +
              (bf2f((unsigned short)(v4 >> 16)) + bf2f((unsigned short)(v5 >> 16))) +
              (bf2f((unsigned short)(v6 >> 16)) + bf2f((unsigned short)(v7 >> 16)));
    }
    for (; j < dg; ++j) {
        unsigned vv = x[(size_t)row[j] * U2STRIDE + off];
        a0 += bf2f((unsigned short)(vv & 0xffff));
        a1 += bf2f((unsigned short)(vv >> 16));
    }
    unsigned o = (unsigned)f2bf(a0) | ((unsigned)f2bf(a1) << 16);
    out[(size_t)wid * U2STRIDE + off] = o;
}

// ---------------------------------------------------------------------------
// bf16 MFMA GEMM, no LDS. One wave per block computes a 32x64 output tile
// (2 row-groups x 4 n-tiles of 16x16), K fully unrolled in steps of 32.
// Wt is W transposed: [N=256][K] bf16. Grid: ceil(M/32) * 4 blocks.
// Fragment mapping (mfma_f32_16x16x32_bf16, HW-verified):
//   A: row = lane&15, k = (lane>>4)*8 + j ; B: col = lane&15, same k
//   D: col = lane&15, row = (lane>>4)*4 + reg
// ---------------------------------------------------------------------------
template <int KSTEPS, bool RELU, bool F32OUT>
__global__ __launch_bounds__(64) void gemm_mfma(const unsigned short* __restrict__ A,
                                                const unsigned short* __restrict__ Wt,
                                                const float* __restrict__ bias,
                                                void* __restrict__ Cout) {
    constexpr int K = KSTEPS * 32;
    int bid = blockIdx.x;
    int rowtile = bid >> 2;
    int nq = bid & 3;
    int r0 = rowtile * 32;
    int lane = threadIdx.x;
    int lrow = lane & 15;
    int lkg = lane >> 4;

    const short8* Ap0 = (const short8*)(A + (size_t)(r0 + lrow) * K + lkg * 8);
    const short8* Ap1 = (const short8*)(A + (size_t)(r0 + 16 + lrow) * K + lkg * 8);
    int n0 = nq * 64;
    const short8* Bp = (const short8*)(Wt + (size_t)(n0 + lrow) * K + lkg * 8);
    // offsets in short8 units: k-step = 4; n-tile stride = 16*K/8 = 2*K
    f32x4 acc[2][4] = {};

#pragma unroll
    for (int ks = 0; ks < KSTEPS; ++ks) {
        short8 a0 = Ap0[ks * 4];
        short8 a1 = Ap1[ks * 4];
        short8 b0 = Bp[ks * 4 + 0 * 2 * K];
        short8 b1 = Bp[ks * 4 + 1 * 2 * K];
        short8 b2 = Bp[ks * 4 + 2 * 2 * K];
        short8 b3 = Bp[ks * 4 + 3 * 2 * K];
        acc[0][0] = __builtin_amdgcn_mfma_f32_16x16x32_bf16(a0, b0, acc[0][0], 0, 0, 0);
        acc[0][1] = __builtin_amdgcn_mfma_f32_16x16x32_bf16(a0, b1, acc[0][1], 0, 0, 0);
        acc[0][2] = __builtin_amdgcn_mfma_f32_16x16x32_bf16(a0, b2, acc[0][2], 0, 0, 0);
        acc[0][3] = __builtin_amdgcn_mfma_f32_16x16x32_bf16(a0, b3, acc[0][3], 0, 0, 0);
        acc[1][0] = __builtin_amdgcn_mfma_f32_16x16x32_bf16(a1, b0, acc[1][0], 0, 0, 0);
        acc[1][1] = __builtin_amdgcn_mfma_f32_16x16x32_bf16(a1, b1, acc[1][1], 0, 0, 0);
        acc[1][2] = __builtin_amdgcn_mfma_f32_16x16x32_bf16(a1, b2, acc[1][2], 0, 0, 0);
        acc[1][3] = __builtin_amdgcn_mfma_f32_16x16x32_bf16(a1, b3, acc[1][3], 0, 0, 0);
    }

#pragma unroll
    for (int rg = 0; rg < 2; ++rg) {
        int orow = r0 + rg * 16 + lkg * 4;
#pragma unroll
        for (int nt = 0; nt < 4; ++nt) {
            int c = n0 + nt * 16 + lrow;
            float bv = bias[c];
#pragma unroll
            for (int r = 0; r < 4; ++r) {
                int grow = orow + r;
                if (grow >= N_NODES) continue;
                float v = acc[rg][nt][r] + bv;
                if (RELU) v = fmaxf(v, 0.f);
                if (F32OUT)
                    ((float*)Cout)[(size_t)grow * 256 + c] = v;
                else
                    ((unsigned short*)Cout)[(size_t)grow * 256 + c] = f2bf(v);
            }
        }
    }
}

// ---------------------------------------------------------------------------
extern "C" void kernel_launch(void* const* d_in, const int* in_sizes, int n_in,
                              void* d_out, int out_size, void* d_ws, size_t ws_size,
                              hipStream_t stream) {
    const float* x   = (const float*)d_in[0];
    const int*   ei  = (const int*)d_in[1];
    const int*   src = ei;
    const int*   dst = ei + N_EDGES;
    const float* W0a = (const float*)d_in[2];
    const float* b0a = (const float*)d_in[3];
    const float* W0b = (const float*)d_in[4];
    const float* b0b = (const float*)d_in[5];
    const float* W1a = (const float*)d_in[6];
    const float* b1a = (const float*)d_in[7];
    const float* W1b = (const float*)d_in[8];
    const float* b1b = (const float*)d_in[9];
    const float* W2a = (const float*)d_in[10];
    const float* b2a = (const float*)d_in[11];
    const float* W2b = (const float*)d_in[12];
    const float* b2b = (const float*)d_in[13];

    char* ws = (char*)d_ws;
    size_t off = 0;
    auto alloc = [&](size_t bytes) {
        void* p = ws + off;
        off += (bytes + 255) & ~(size_t)255;
        return p;
    };
    unsigned short* xb    = (unsigned short*)alloc((size_t)N_NODES * 128 * 2);
    unsigned short* B0    = (unsigned short*)alloc((size_t)N_NODES * 256 * 2);
    unsigned short* B1    = (unsigned short*)alloc((size_t)N_NODES * 256 * 2);
    unsigned short* B2    = (unsigned short*)alloc((size_t)N_NODES * 256 * 2);
    unsigned short* Wt0a  = (unsigned short*)alloc(256 * 128 * 2);
    unsigned short* Wt0b  = (unsigned short*)alloc(256 * 256 * 2);
    unsigned short* Wt1a  = (unsigned short*)alloc(256 * 256 * 2);
    unsigned short* Wt1b  = (unsigned short*)alloc(256 * 256 * 2);
    unsigned short* Wt2a  = (unsigned short*)alloc(256 * 256 * 2);
    unsigned short* Wt2b  = (unsigned short*)alloc(256 * 256 * 2);
    int*            deg   = (int*)alloc(N_NODES * 4);
    unsigned short* ell   = (unsigned short*)alloc((size_t)N_NODES * ELL_W * 2);
    int*            gCur  = (int*)alloc(NB * 4);
    unsigned*       gBkt  = (unsigned*)alloc((size_t)NB * BCAP * 4);

    dim3 gatherGrid1((N_NODES + 3) / 4, 1);       // C=128: one half
    dim3 gatherGrid2((N_NODES + 3) / 4, 2);       // C=256: two halves
    int gemmBlocks = ((N_NODES + 31) / 32) * 4;   // 1252

    // ---- ELL build: zero cursors -> bin -> build (no global atomic scatter) ----
    zero_cursor<<<1, 256, 0, stream>>>(gCur);
    bin_edges<<<(N_EDGES + CHUNK - 1) / CHUNK, 256, 0, stream>>>(src, dst, gCur, gBkt);
    build_ell<<<NB, 256, 0, stream>>>(gBkt, gCur, ell, deg);

    // ---- Precision conversion ----
    cvt_x_kernel<<<(N_NODES * 128 / 4 + 255) / 256, 256, 0, stream>>>(
        (const float4*)x, (ushort4*)xb, N_NODES * 128 / 4);
    WList wl;
    wl.src[0] = W0a; wl.dst[0] = Wt0a; wl.K[0] = 128;
    wl.src[1] = W0b; wl.dst[1] = Wt0b; wl.K[1] = 256;
    wl.src[2] = W1a; wl.dst[2] = Wt1a; wl.K[2] = 256;
    wl.src[3] = W1b; wl.dst[3] = Wt1b; wl.K[3] = 256;
    wl.src[4] = W2a; wl.dst[4] = Wt2a; wl.K[4] = 256;
    wl.src[5] = W2b; wl.dst[5] = Wt2b; wl.K[5] = 256;
    int total = 0;
    for (int i = 0; i < 6; ++i) { wl.off[i] = total; total += wl.K[i] * 256; }
    wl.off[6] = total;
    cvt_w_kernel<<<(total + 255) / 256, 256, 0, stream>>>(wl, total);

    // ---- Layer 0 (C_in = 128) ----
    gather_ell<64><<<gatherGrid1, 256, 0, stream>>>((const unsigned*)xb, ell, deg, (unsigned*)B0);
    gemm_mfma<4, true, false><<<gemmBlocks, 64, 0, stream>>>(B0, Wt0a, b0a, B1);
    gemm_mfma<8, true, false><<<gemmBlocks, 64, 0, stream>>>(B1, Wt0b, b0b, B2);
    // ---- Layer 1 (C = 256) ----
    gather_ell<128><<<gatherGrid2, 256, 0, stream>>>((const unsigned*)B2, ell, deg, (unsigned*)B0);
    gemm_mfma<8, true, false><<<gemmBlocks, 64, 0, stream>>>(B0, Wt1a, b1a, B1);
    gemm_mfma<8, true, false><<<gemmBlocks, 64, 0, stream>>>(B1, Wt1b, b1b, B2);
    // ---- Layer 2 (C = 256, final out fp32, no ReLU) ----
    gather_ell<128><<<gatherGrid2, 256, 0, stream>>>((const unsigned*)B2, ell, deg, (unsigned*)B0);
    gemm_mfma<8, true, false><<<gemmBlocks, 64, 0, stream>>>(B0, Wt2a, b2a, B1);
    gemm_mfma<8, false, true><<<gemmBlocks, 64, 0, stream>>>(B1, Wt2b, b2b, d_out);
}

// Round 7
// 163.050 us; speedup vs baseline: 1.2421x; 1.0993x over previous
//
#include <hip/hip_runtime.h>

#define N_NODES 10000
#define N_EDGES 640000
#define ELL_W   128    // max in-degree capacity; Poisson(64) => P(deg>127) ~ 1e-14
#define NB      157    // buckets of 64 nodes: bucket = dst >> 6
#define BCAP    4600   // per-bucket capacity (mean 4076, +8 sigma)
#define LCAP    80     // per-wg per-bucket LDS bin capacity (mean ~16, +16 sigma)
#define CHUNK   2500   // edges per workgroup in phase 1 (256 wgs * 2500 = 640000)

typedef short short8 __attribute__((ext_vector_type(8)));
typedef float f32x4 __attribute__((ext_vector_type(4)));

__device__ inline float bf2f(unsigned short u) {
    return __uint_as_float(((unsigned)u) << 16);
}
// round-to-nearest-even f32 -> bf16 (data here is never NaN)
__device__ inline unsigned short f2bf(float f) {
    unsigned u = __float_as_uint(f);
    u += 0x7fffu + ((u >> 16) & 1u);
    return (unsigned short)(u >> 16);
}

// ---------------------------------------------------------------------------
// Tiny zero kernel for bucket cursors (hipMemsetAsync's runtime kernel was 43us)
// ---------------------------------------------------------------------------
__global__ __launch_bounds__(256) void zero_cursor(int* __restrict__ g) {
    if (threadIdx.x < NB) g[threadIdx.x] = 0;
}

// ---------------------------------------------------------------------------
// Phase 1: bin edges by dst bucket (dst>>6) via LDS, coalesced flush.
// Packed word: (src << 6) | (dst & 63). Flush is wave-parallel over buckets.
// ---------------------------------------------------------------------------
__global__ __launch_bounds__(256) void bin_edges(const int* __restrict__ src,
                                                 const int* __restrict__ dst,
                                                 int* __restrict__ gCursor,
                                                 unsigned* __restrict__ gBucket) {
    __shared__ unsigned bins[NB][LCAP];
    __shared__ int cnt[NB];
    __shared__ int base[NB];
    int t = threadIdx.x;
    for (int i = t; i < NB; i += 256) cnt[i] = 0;
    __syncthreads();

    int e0 = blockIdx.x * CHUNK;
    int e1 = min(e0 + CHUNK, N_EDGES);
    for (int e = e0 + t; e < e1; e += 256) {
        int d = dst[e];
        int b = d >> 6;
        unsigned pk = ((unsigned)src[e] << 6) | (unsigned)(d & 63);
        int p = atomicAdd(&cnt[b], 1);
        if (p < LCAP) bins[b][p] = pk;
    }
    __syncthreads();
    for (int i = t; i < NB; i += 256) {
        int c = min(cnt[i], LCAP);
        cnt[i] = c;
        base[i] = atomicAdd(&gCursor[i], c);
    }
    __syncthreads();
    int wave = t >> 6, lane = t & 63;
    for (int b = wave; b < NB; b += 4) {
        int ba = base[b];
        int n = min(cnt[b], max(0, BCAP - ba));
        for (int i = lane; i < n; i += 64)
            gBucket[(size_t)b * BCAP + ba + i] = bins[b][i];
    }
}

// ---------------------------------------------------------------------------
// Phase 2: one workgroup per bucket; build 64 ELL rows in LDS, write coalesced.
// ---------------------------------------------------------------------------
__global__ __launch_bounds__(256) void build_ell(const unsigned* __restrict__ gBucket,
                                                 const int* __restrict__ gCursor,
                                                 unsigned short* __restrict__ ell,
                                                 int* __restrict__ deg) {
    __shared__ unsigned short rows[64 * ELL_W];  // 16 KB
    __shared__ int ldeg[64];
    int b = blockIdx.x;
    int t = threadIdx.x;
    for (int i = t; i < 64; i += 256) ldeg[i] = 0;
    __syncthreads();

    int n = min(gCursor[b], BCAP);
    const unsigned* bk = gBucket + (size_t)b * BCAP;
    for (int i = t; i < n; i += 256) {
        unsigned pk = bk[i];
        int local = pk & 63;
        int s = pk >> 6;
        int p = atomicAdd(&ldeg[local], 1);
        if (p < ELL_W) rows[local * ELL_W + p] = (unsigned short)s;
    }
    __syncthreads();

    int node0 = b * 64;
    int nNodes = min(64, N_NODES - node0);
    if (nNodes <= 0) return;
    for (int i = t; i < nNodes; i += 256)
        deg[node0 + i] = min(ldeg[i], ELL_W);
    int totalVec = nNodes * (ELL_W / 8);
    short8* dstv = (short8*)(ell + (size_t)node0 * ELL_W);
    const short8* srcv = (const short8*)rows;
    for (int i = t; i < totalVec; i += 256) dstv[i] = srcv[i];
}

// ---------------------------------------------------------------------------
// Conversions: x fp32 -> bf16; weights fp32 [K][N] -> bf16 transposed [N][K]
// ---------------------------------------------------------------------------
__global__ __launch_bounds__(256) void cvt_x_kernel(const float4* __restrict__ x,
                                                    ushort4* __restrict__ xb, int n4) {
    int i = blockIdx.x * 256 + threadIdx.x;
    if (i >= n4) return;
    float4 v = x[i];
    ushort4 o;
    o.x = f2bf(v.x); o.y = f2bf(v.y); o.z = f2bf(v.z); o.w = f2bf(v.w);
    xb[i] = o;
}

struct WList {
    const float* src[6];
    unsigned short* dst[6];
    int K[6];
    int off[7];  // element offsets, N == 256 for all
};

__global__ __launch_bounds__(256) void cvt_w_kernel(WList wl, int total) {
    int idx = blockIdx.x * 256 + threadIdx.x;
    if (idx >= total) return;
    int w = 0;
    while (idx >= wl.off[w + 1]) ++w;
    int r = idx - wl.off[w];
    int k = r >> 8;          // N = 256
    int n = r & 255;
    wl.dst[w][(size_t)n * wl.K[w] + k] = f2bf(wl.src[w][r]);
}

// ---------------------------------------------------------------------------
// Gather aggregation (bf16, fp32 accumulate), 128 channels per wave-pass so the
// random-row working set (2.56 MB) stays mostly L2-resident per XCD.
// One wave per (node, half). 16 outstanding loads per iteration for MLP.
// ---------------------------------------------------------------------------
template <int U2STRIDE>
__global__ __launch_bounds__(256) void gather_ell(const unsigned* __restrict__ x,
                                                  const unsigned short* __restrict__ ell,
                                                  const int* __restrict__ deg,
                                                  unsigned* __restrict__ out) {
    int wid = (blockIdx.x * 256 + threadIdx.x) >> 6;  // node id
    int lane = threadIdx.x & 63;
    if (wid >= N_NODES) return;
    int off = blockIdx.y * 64 + lane;  // uint offset within row

    unsigned v = x[(size_t)wid * U2STRIDE + off];
    float a0 = bf2f((unsigned short)(v & 0xffff));
    float a1 = bf2f((unsigned short)(v >> 16));

    int dg = min(deg[wid], ELL_W);
    const unsigned short* row = ell + (size_t)wid * ELL_W;

    int j = 0;
    for (; j + 16 <= dg; j += 16) {
        short8 iA = *(const short8*)(row + j);
        short8 iB = *(const short8*)(row + j + 8);
        unsigned vv[16];
#pragma unroll
        for (int q = 0; q < 8; ++q)
            vv[q] = x[(size_t)(unsigned short)iA[q] * U2STRIDE + off];
#pragma unroll
        for (int q = 0; q < 8; ++q)
            vv[8 + q] = x[(size_t)(unsigned short)iB[q] * U2STRIDE + off];
#pragma unroll
        for (int q = 0; q < 16; ++q) {
            a0 += bf2f((unsigned short)(vv[q] & 0xffff));
            a1 += bf2f((unsigned short)(vv[q] >> 16));
        }
    }
    for (; j + 4 <= dg; j += 4) {
        ushort4 sA = *(const ushort4*)(row + j);
        unsigned v0 = x[(size_t)sA.x * U2STRIDE + off];
        unsigned v1 = x[(size_t)sA.y * U2STRIDE + off];
        unsigned v2 = x[(size_t)sA.z * U2STRIDE + off];
        unsigned v3 = x[(size_t)sA.w * U2STRIDE + off];
        a0 += (bf2f((unsigned short)(v0 & 0xffff)) + bf2f((unsigned short)(v1 & 0xffff))) +
              (bf2f((unsigned short)(v2 & 0xffff)) + bf2f((unsigned short)(v3 & 0xffff)));
        a1 += (bf2f((unsigned short)(v0 >> 16)) + bf2f((unsigned short)(v1 >> 16))) +
              (bf2f((unsigned short)(v2 >> 16)) + bf2f((unsigned short)(v3 >> 16)));
    }
    for (; j < dg; ++j) {
        unsigned vv = x[(size_t)row[j] * U2STRIDE + off];
        a0 += bf2f((unsigned short)(vv & 0xffff));
        a1 += bf2f((unsigned short)(vv >> 16));
    }
    unsigned o = (unsigned)f2bf(a0) | ((unsigned)f2bf(a1) << 16);
    out[(size_t)wid * U2STRIDE + off] = o;
}

// ---------------------------------------------------------------------------
// bf16 MFMA GEMM with LDS-staged B. Block = 256 thr (4 waves) = 128 rows x 64
// cols. The B quarter (64 x K) is staged once into LDS (pitch K+8 to spread
// b128 reads across bank-quads) and shared by all 4 waves; each wave computes
// a 32x64 tile (2 row-groups x 4 n-tiles), K fully unrolled in steps of 32.
// Grid: ceil(M/128) * 4. Wt is [N=256][K] bf16.
// Fragment mapping (mfma_f32_16x16x32_bf16, HW-verified):
//   A: row = lane&15, k = (lane>>4)*8 + j ; B: col = lane&15, same k
//   D: col = lane&15, row = (lane>>4)*4 + reg
// ---------------------------------------------------------------------------
template <int KSTEPS, bool RELU, bool F32OUT>
__global__ __launch_bounds__(256) void gemm_mfma(const unsigned short* __restrict__ A,
                                                 const unsigned short* __restrict__ Wt,
                                                 const float* __restrict__ bias,
                                                 void* __restrict__ Cout) {
    constexpr int K = KSTEPS * 32;
    constexpr int LP = K + 8;                  // LDS pitch (bf16 elems)
    __shared__ unsigned short Bs[64 * LP];     // K=256: 33 KB

    int bid = blockIdx.x;
    int rowblk = bid >> 2;
    int nq = bid & 3;
    int r0 = rowblk * 128;
    int n0 = nq * 64;
    int tid = threadIdx.x;

    // ---- stage B quarter: Wt[n0 .. n0+63][0..K) -> Bs, coalesced short8 ----
    {
        constexpr int V = 64 * (K / 8);
        const short8* srcv = (const short8*)(Wt + (size_t)n0 * K);
        for (int i = tid; i < V; i += 256) {
            int r = i / (K / 8);
            int c = i % (K / 8);
            *(short8*)&Bs[r * LP + c * 8] = srcv[i];
        }
    }
    __syncthreads();

    int wave = tid >> 6, lane = tid & 63;
    int lrow = lane & 15;
    int lkg = lane >> 4;
    int wr0 = r0 + wave * 32;
    if (wr0 >= N_NODES) return;  // after barrier; whole-wave uniform exit

    const short8* Ap0 = (const short8*)(A + (size_t)(wr0 + lrow) * K + lkg * 8);
    const short8* Ap1 = (const short8*)(A + (size_t)(wr0 + 16 + lrow) * K + lkg * 8);
    f32x4 acc[2][4] = {};

#pragma unroll
    for (int ks = 0; ks < KSTEPS; ++ks) {
        short8 a0 = Ap0[ks * 4];
        short8 a1 = Ap1[ks * 4];
        short8 b0 = *(const short8*)&Bs[(0 * 16 + lrow) * LP + ks * 32 + lkg * 8];
        short8 b1 = *(const short8*)&Bs[(1 * 16 + lrow) * LP + ks * 32 + lkg * 8];
        short8 b2 = *(const short8*)&Bs[(2 * 16 + lrow) * LP + ks * 32 + lkg * 8];
        short8 b3 = *(const short8*)&Bs[(3 * 16 + lrow) * LP + ks * 32 + lkg * 8];
        acc[0][0] = __builtin_amdgcn_mfma_f32_16x16x32_bf16(a0, b0, acc[0][0], 0, 0, 0);
        acc[0][1] = __builtin_amdgcn_mfma_f32_16x16x32_bf16(a0, b1, acc[0][1], 0, 0, 0);
        acc[0][2] = __builtin_amdgcn_mfma_f32_16x16x32_bf16(a0, b2, acc[0][2], 0, 0, 0);
        acc[0][3] = __builtin_amdgcn_mfma_f32_16x16x32_bf16(a0, b3, acc[0][3], 0, 0, 0);
        acc[1][0] = __builtin_amdgcn_mfma_f32_16x16x32_bf16(a1, b0, acc[1][0], 0, 0, 0);
        acc[1][1] = __builtin_amdgcn_mfma_f32_16x16x32_bf16(a1, b1, acc[1][1], 0, 0, 0);
        acc[1][2] = __builtin_amdgcn_mfma_f32_16x16x32_bf16(a1, b2, acc[1][2], 0, 0, 0);
        acc[1][3] = __builtin_amdgcn_mfma_f32_16x16x32_bf16(a1, b3, acc[1][3], 0, 0, 0);
    }

#pragma unroll
    for (int rg = 0; rg < 2; ++rg) {
        int orow = wr0 + rg * 16 + lkg * 4;
#pragma unroll
        for (int nt = 0; nt < 4; ++nt) {
            int c = n0 + nt * 16 + lrow;
            float bv = bias[c];
#pragma unroll
            for (int r = 0; r < 4; ++r) {
                int grow = orow + r;
                if (grow >= N_NODES) continue;
                float v = acc[rg][nt][r] + bv;
                if (RELU) v = fmaxf(v, 0.f);
                if (F32OUT)
                    ((float*)Cout)[(size_t)grow * 256 + c] = v;
                else
                    ((unsigned short*)Cout)[(size_t)grow * 256 + c] = f2bf(v);
            }
        }
    }
}

// ---------------------------------------------------------------------------
extern "C" void kernel_launch(void* const* d_in, const int* in_sizes, int n_in,
                              void* d_out, int out_size, void* d_ws, size_t ws_size,
                              hipStream_t stream) {
    const float* x   = (const float*)d_in[0];
    const int*   ei  = (const int*)d_in[1];
    const int*   src = ei;
    const int*   dst = ei + N_EDGES;
    const float* W0a = (const float*)d_in[2];
    const float* b0a = (const float*)d_in[3];
    const float* W0b = (const float*)d_in[4];
    const float* b0b = (const float*)d_in[5];
    const float* W1a = (const float*)d_in[6];
    const float* b1a = (const float*)d_in[7];
    const float* W1b = (const float*)d_in[8];
    const float* b1b = (const float*)d_in[9];
    const float* W2a = (const float*)d_in[10];
    const float* b2a = (const float*)d_in[11];
    const float* W2b = (const float*)d_in[12];
    const float* b2b = (const float*)d_in[13];

    char* ws = (char*)d_ws;
    size_t off = 0;
    auto alloc = [&](size_t bytes) {
        void* p = ws + off;
        off += (bytes + 255) & ~(size_t)255;
        return p;
    };
    unsigned short* xb    = (unsigned short*)alloc((size_t)N_NODES * 128 * 2);
    unsigned short* B0    = (unsigned short*)alloc((size_t)N_NODES * 256 * 2);
    unsigned short* B1    = (unsigned short*)alloc((size_t)N_NODES * 256 * 2);
    unsigned short* B2    = (unsigned short*)alloc((size_t)N_NODES * 256 * 2);
    unsigned short* Wt0a  = (unsigned short*)alloc(256 * 128 * 2);
    unsigned short* Wt0b  = (unsigned short*)alloc(256 * 256 * 2);
    unsigned short* Wt1a  = (unsigned short*)alloc(256 * 256 * 2);
    unsigned short* Wt1b  = (unsigned short*)alloc(256 * 256 * 2);
    unsigned short* Wt2a  = (unsigned short*)alloc(256 * 256 * 2);
    unsigned short* Wt2b  = (unsigned short*)alloc(256 * 256 * 2);
    int*            deg   = (int*)alloc(N_NODES * 4);
    unsigned short* ell   = (unsigned short*)alloc((size_t)N_NODES * ELL_W * 2);
    int*            gCur  = (int*)alloc(NB * 4);
    unsigned*       gBkt  = (unsigned*)alloc((size_t)NB * BCAP * 4);

    dim3 gatherGrid1((N_NODES + 3) / 4, 1);        // C=128: one half
    dim3 gatherGrid2((N_NODES + 3) / 4, 2);        // C=256: two halves
    int gemmBlocks = ((N_NODES + 127) / 128) * 4;  // 316

    // ---- ELL build: zero cursors -> bin -> build ----
    zero_cursor<<<1, 256, 0, stream>>>(gCur);
    bin_edges<<<(N_EDGES + CHUNK - 1) / CHUNK, 256, 0, stream>>>(src, dst, gCur, gBkt);
    build_ell<<<NB, 256, 0, stream>>>(gBkt, gCur, ell, deg);

    // ---- Precision conversion ----
    cvt_x_kernel<<<(N_NODES * 128 / 4 + 255) / 256, 256, 0, stream>>>(
        (const float4*)x, (ushort4*)xb, N_NODES * 128 / 4);
    WList wl;
    wl.src[0] = W0a; wl.dst[0] = Wt0a; wl.K[0] = 128;
    wl.src[1] = W0b; wl.dst[1] = Wt0b; wl.K[1] = 256;
    wl.src[2] = W1a; wl.dst[2] = Wt1a; wl.K[2] = 256;
    wl.src[3] = W1b; wl.dst[3] = Wt1b; wl.K[3] = 256;
    wl.src[4] = W2a; wl.dst[4] = Wt2a; wl.K[4] = 256;
    wl.src[5] = W2b; wl.dst[5] = Wt2b; wl.K[5] = 256;
    int total = 0;
    for (int i = 0; i < 6; ++i) { wl.off[i] = total; total += wl.K[i] * 256; }
    wl.off[6] = total;
    cvt_w_kernel<<<(total + 255) / 256, 256, 0, stream>>>(wl, total);

    // ---- Layer 0 (C_in = 128) ----
    gather_ell<64><<<gatherGrid1, 256, 0, stream>>>((const unsigned*)xb, ell, deg, (unsigned*)B0);
    gemm_mfma<4, true, false><<<gemmBlocks, 256, 0, stream>>>(B0, Wt0a, b0a, B1);
    gemm_mfma<8, true, false><<<gemmBlocks, 256, 0, stream>>>(B1, Wt0b, b0b, B2);
    // ---- Layer 1 (C = 256) ----
    gather_ell<128><<<gatherGrid2, 256, 0, stream>>>((const unsigned*)B2, ell, deg, (unsigned*)B0);
    gemm_mfma<8, true, false><<<gemmBlocks, 256, 0, stream>>>(B0, Wt1a, b1a, B1);
    gemm_mfma<8, true, false><<<gemmBlocks, 256, 0, stream>>>(B1, Wt1b, b1b, B2);
    // ---- Layer 2 (C = 256, final out fp32, no ReLU) ----
    gather_ell<128><<<gatherGrid2, 256, 0, stream>>>((const unsigned*)B2, ell, deg, (unsigned*)B0);
    gemm_mfma<8, true, false><<<gemmBlocks, 256, 0, stream>>>(B0, Wt2a, b2a, B1);
    gemm_mfma<8, false, true><<<gemmBlocks, 256, 0, stream>>>(B1, Wt2b, b2b, d_out);
}

// Round 8
// 161.134 us; speedup vs baseline: 1.2568x; 1.0119x over previous
//
#include <hip/hip_runtime.h>

#define N_NODES 10000
#define N_EDGES 640000
#define ELL_W   128    // max in-degree capacity; Poisson(64) => P(deg>127) ~ 1e-14
#define NB      157    // buckets of 64 nodes: bucket = dst >> 6
#define BCAP    4600   // per-bucket capacity (mean 4076, +8 sigma)
#define LCAP    80     // per-wg per-bucket LDS bin capacity (mean ~16, +16 sigma)
#define CHUNK   2500   // edges per workgroup in phase 1 (256 wgs * 2500 = 640000)

typedef short short8 __attribute__((ext_vector_type(8)));
typedef float f32x4 __attribute__((ext_vector_type(4)));

__device__ inline float bf2f(unsigned short u) {
    return __uint_as_float(((unsigned)u) << 16);
}
// round-to-nearest-even f32 -> bf16 (data here is never NaN)
__device__ inline unsigned short f2bf(float f) {
    unsigned u = __float_as_uint(f);
    u += 0x7fffu + ((u >> 16) & 1u);
    return (unsigned short)(u >> 16);
}

// ---------------------------------------------------------------------------
// Phase 1: bin edges by dst bucket (dst>>6) via LDS, coalesced flush.
// Packed word: (src << 6) | (dst & 63). Flush is wave-parallel over buckets.
// ---------------------------------------------------------------------------
__global__ __launch_bounds__(256) void bin_edges(const int* __restrict__ src,
                                                 const int* __restrict__ dst,
                                                 int* __restrict__ gCursor,
                                                 unsigned* __restrict__ gBucket) {
    __shared__ unsigned bins[NB][LCAP];
    __shared__ int cnt[NB];
    __shared__ int base[NB];
    int t = threadIdx.x;
    for (int i = t; i < NB; i += 256) cnt[i] = 0;
    __syncthreads();

    int e0 = blockIdx.x * CHUNK;
    int e1 = min(e0 + CHUNK, N_EDGES);
    for (int e = e0 + t; e < e1; e += 256) {
        int d = dst[e];
        int b = d >> 6;
        unsigned pk = ((unsigned)src[e] << 6) | (unsigned)(d & 63);
        int p = atomicAdd(&cnt[b], 1);
        if (p < LCAP) bins[b][p] = pk;
    }
    __syncthreads();
    for (int i = t; i < NB; i += 256) {
        int c = min(cnt[i], LCAP);
        cnt[i] = c;
        base[i] = atomicAdd(&gCursor[i], c);
    }
    __syncthreads();
    int wave = t >> 6, lane = t & 63;
    for (int b = wave; b < NB; b += 4) {
        int ba = base[b];
        int n = min(cnt[b], max(0, BCAP - ba));
        for (int i = lane; i < n; i += 64)
            gBucket[(size_t)b * BCAP + ba + i] = bins[b][i];
    }
}

// ---------------------------------------------------------------------------
// Phase 2: one workgroup per bucket; build 64 ELL rows in LDS, write coalesced.
// ---------------------------------------------------------------------------
__global__ __launch_bounds__(256) void build_ell(const unsigned* __restrict__ gBucket,
                                                 const int* __restrict__ gCursor,
                                                 unsigned short* __restrict__ ell,
                                                 int* __restrict__ deg) {
    __shared__ unsigned short rows[64 * ELL_W];  // 16 KB
    __shared__ int ldeg[64];
    int b = blockIdx.x;
    int t = threadIdx.x;
    for (int i = t; i < 64; i += 256) ldeg[i] = 0;
    __syncthreads();

    int n = min(gCursor[b], BCAP);
    const unsigned* bk = gBucket + (size_t)b * BCAP;
    for (int i = t; i < n; i += 256) {
        unsigned pk = bk[i];
        int local = pk & 63;
        int s = pk >> 6;
        int p = atomicAdd(&ldeg[local], 1);
        if (p < ELL_W) rows[local * ELL_W + p] = (unsigned short)s;
    }
    __syncthreads();

    int node0 = b * 64;
    int nNodes = min(64, N_NODES - node0);
    if (nNodes <= 0) return;
    for (int i = t; i < nNodes; i += 256)
        deg[node0 + i] = min(ldeg[i], ELL_W);
    int totalVec = nNodes * (ELL_W / 8);
    short8* dstv = (short8*)(ell + (size_t)node0 * ELL_W);
    const short8* srcv = (const short8*)rows;
    for (int i = t; i < totalVec; i += 256) dstv[i] = srcv[i];
}

// ---------------------------------------------------------------------------
// Combined prep: zero bucket cursors + cvt x fp32->bf16 + cvt/transpose weights
// Task space: [0, n4) = x float4 tasks; [n4, n4+totalW) = weight elements.
// ---------------------------------------------------------------------------
struct WList {
    const float* src[6];
    unsigned short* dst[6];
    int K[6];
    int off[7];  // element offsets, N == 256 for all
};

__global__ __launch_bounds__(256) void prep_kernel(const float4* __restrict__ x,
                                                   ushort4* __restrict__ xb, int n4,
                                                   WList wl, int totalW,
                                                   int* __restrict__ gCursor) {
    int idx = blockIdx.x * 256 + threadIdx.x;
    if (blockIdx.x == 0 && threadIdx.x < NB) gCursor[threadIdx.x] = 0;
    if (idx < n4) {
        float4 v = x[idx];
        ushort4 o;
        o.x = f2bf(v.x); o.y = f2bf(v.y); o.z = f2bf(v.z); o.w = f2bf(v.w);
        xb[idx] = o;
        return;
    }
    int r0 = idx - n4;
    if (r0 >= totalW) return;
    int w = 0;
    while (r0 >= wl.off[w + 1]) ++w;
    int r = r0 - wl.off[w];
    int k = r >> 8;          // N = 256
    int n = r & 255;
    wl.dst[w][(size_t)n * wl.K[w] + k] = f2bf(wl.src[w][r]);
}

// ---------------------------------------------------------------------------
// Gather aggregation (bf16, fp32 accumulate), 128 channels per wave-pass so the
// random-row working set (2.56 MB) stays mostly L2-resident per XCD.
// One wave per (node, half). 16 outstanding loads per iteration for MLP.
// ---------------------------------------------------------------------------
template <int U2STRIDE>
__global__ __launch_bounds__(256) void gather_ell(const unsigned* __restrict__ x,
                                                  const unsigned short* __restrict__ ell,
                                                  const int* __restrict__ deg,
                                                  unsigned* __restrict__ out) {
    int wid = (blockIdx.x * 256 + threadIdx.x) >> 6;  // node id
    int lane = threadIdx.x & 63;
    if (wid >= N_NODES) return;
    int off = blockIdx.y * 64 + lane;  // uint offset within row

    unsigned v = x[(size_t)wid * U2STRIDE + off];
    float a0 = bf2f((unsigned short)(v & 0xffff));
    float a1 = bf2f((unsigned short)(v >> 16));

    int dg = min(deg[wid], ELL_W);
    const unsigned short* row = ell + (size_t)wid * ELL_W;

    int j = 0;
    for (; j + 16 <= dg; j += 16) {
        short8 iA = *(const short8*)(row + j);
        short8 iB = *(const short8*)(row + j + 8);
        unsigned vv[16];
#pragma unroll
        for (int q = 0; q < 8; ++q)
            vv[q] = x[(size_t)(unsigned short)iA[q] * U2STRIDE + off];
#pragma unroll
        for (int q = 0; q < 8; ++q)
            vv[8 + q] = x[(size_t)(unsigned short)iB[q] * U2STRIDE + off];
#pragma unroll
        for (int q = 0; q < 16; ++q) {
            a0 += bf2f((unsigned short)(vv[q] & 0xffff));
            a1 += bf2f((unsigned short)(vv[q] >> 16));
        }
    }
    for (; j + 4 <= dg; j += 4) {
        ushort4 sA = *(const ushort4*)(row + j);
        unsigned v0 = x[(size_t)sA.x * U2STRIDE + off];
        unsigned v1 = x[(size_t)sA.y * U2STRIDE + off];
        unsigned v2 = x[(size_t)sA.z * U2STRIDE + off];
        unsigned v3 = x[(size_t)sA.w * U2STRIDE + off];
        a0 += (bf2f((unsigned short)(v0 & 0xffff)) + bf2f((unsigned short)(v1 & 0xffff))) +
              (bf2f((unsigned short)(v2 & 0xffff)) + bf2f((unsigned short)(v3 & 0xffff)));
        a1 += (bf2f((unsigned short)(v0 >> 16)) + bf2f((unsigned short)(v1 >> 16))) +
              (bf2f((unsigned short)(v2 >> 16)) + bf2f((unsigned short)(v3 >> 16)));
    }
    for (; j < dg; ++j) {
        unsigned vv = x[(size_t)row[j] * U2STRIDE + off];
        a0 += bf2f((unsigned short)(vv & 0xffff));
        a1 += bf2f((unsigned short)(vv >> 16));
    }
    unsigned o = (unsigned)f2bf(a0) | ((unsigned)f2bf(a1) << 16);
    out[(size_t)wid * U2STRIDE + off] = o;
}

// ---------------------------------------------------------------------------
// Fused MLP: out = (ReLU(A @ WA + bA)) @ WB + bB  [+ReLU2] — one dispatch.
// Block = 256 thr = 4 waves; 32 output rows per block; wave w owns col quarter
// w*64..w*64+63 in BOTH stages. Hidden (32x256 bf16) staged in LDS, pitch 264
// (conflict-spread b128 reads). WtA/WtB are [N=256][K] bf16 (L2-resident).
// MFMA fragment mapping (mfma_f32_16x16x32_bf16, HW-verified):
//   A: row = lane&15, k = (lane>>4)*8 + j ; B: col = lane&15, same k
//   D: col = lane&15, row = (lane>>4)*4 + reg
// ---------------------------------------------------------------------------
template <int KSTEPS, bool RELU2, bool F32OUT>
__global__ __launch_bounds__(256) void mlp_mfma(const unsigned short* __restrict__ A,
                                                const unsigned short* __restrict__ WtA,
                                                const float* __restrict__ biasA,
                                                const unsigned short* __restrict__ WtB,
                                                const float* __restrict__ biasB,
                                                void* __restrict__ Cout) {
    constexpr int K1 = KSTEPS * 32;
    constexpr int LP = 264;  // LDS pitch in bf16 elems (528 B)
    __shared__ unsigned short hid[32 * LP];  // 16.5 KB

    int r0 = blockIdx.x * 32;
    int tid = threadIdx.x;
    int lane = tid & 63;
    int nq = tid >> 6;      // wave id = column quarter
    int lrow = lane & 15;
    int lkg = lane >> 4;
    int n0 = nq * 64;

    // ---- stage 1: hidden = ReLU(A @ WA + bA)
    {
        const short8* Ap0 = (const short8*)(A + (size_t)(r0 + lrow) * K1 + lkg * 8);
        const short8* Ap1 = (const short8*)(A + (size_t)(r0 + 16 + lrow) * K1 + lkg * 8);
        const short8* Bp = (const short8*)(WtA + (size_t)(n0 + lrow) * K1 + lkg * 8);
        f32x4 acc[2][4] = {};
#pragma unroll
        for (int ks = 0; ks < KSTEPS; ++ks) {
            short8 a0 = Ap0[ks * 4];
            short8 a1 = Ap1[ks * 4];
            short8 b0 = Bp[ks * 4 + 0 * 2 * K1];
            short8 b1 = Bp[ks * 4 + 1 * 2 * K1];
            short8 b2 = Bp[ks * 4 + 2 * 2 * K1];
            short8 b3 = Bp[ks * 4 + 3 * 2 * K1];
            acc[0][0] = __builtin_amdgcn_mfma_f32_16x16x32_bf16(a0, b0, acc[0][0], 0, 0, 0);
            acc[0][1] = __builtin_amdgcn_mfma_f32_16x16x32_bf16(a0, b1, acc[0][1], 0, 0, 0);
            acc[0][2] = __builtin_amdgcn_mfma_f32_16x16x32_bf16(a0, b2, acc[0][2], 0, 0, 0);
            acc[0][3] = __builtin_amdgcn_mfma_f32_16x16x32_bf16(a0, b3, acc[0][3], 0, 0, 0);
            acc[1][0] = __builtin_amdgcn_mfma_f32_16x16x32_bf16(a1, b0, acc[1][0], 0, 0, 0);
            acc[1][1] = __builtin_amdgcn_mfma_f32_16x16x32_bf16(a1, b1, acc[1][1], 0, 0, 0);
            acc[1][2] = __builtin_amdgcn_mfma_f32_16x16x32_bf16(a1, b2, acc[1][2], 0, 0, 0);
            acc[1][3] = __builtin_amdgcn_mfma_f32_16x16x32_bf16(a1, b3, acc[1][3], 0, 0, 0);
        }
#pragma unroll
        for (int rg = 0; rg < 2; ++rg) {
            int row = rg * 16 + lkg * 4;
#pragma unroll
            for (int nt = 0; nt < 4; ++nt) {
                int c = n0 + nt * 16 + lrow;
                float bv = biasA[c];
#pragma unroll
                for (int r = 0; r < 4; ++r) {
                    float v = fmaxf(acc[rg][nt][r] + bv, 0.f);
                    hid[(row + r) * LP + c] = f2bf(v);
                }
            }
        }
    }
    __syncthreads();

    // ---- stage 2: out = hidden @ WB + bB
    {
        const short8* Bp = (const short8*)(WtB + (size_t)(n0 + lrow) * 256 + lkg * 8);
        f32x4 acc[2][4] = {};
#pragma unroll
        for (int ks = 0; ks < 8; ++ks) {
            short8 a0 = *(const short8*)&hid[lrow * LP + ks * 32 + lkg * 8];
            short8 a1 = *(const short8*)&hid[(16 + lrow) * LP + ks * 32 + lkg * 8];
            short8 b0 = Bp[ks * 4 + 0 * 2 * 256];
            short8 b1 = Bp[ks * 4 + 1 * 2 * 256];
            short8 b2 = Bp[ks * 4 + 2 * 2 * 256];
            short8 b3 = Bp[ks * 4 + 3 * 2 * 256];
            acc[0][0] = __builtin_amdgcn_mfma_f32_16x16x32_bf16(a0, b0, acc[0][0], 0, 0, 0);
            acc[0][1] = __builtin_amdgcn_mfma_f32_16x16x32_bf16(a0, b1, acc[0][1], 0, 0, 0);
            acc[0][2] = __builtin_amdgcn_mfma_f32_16x16x32_bf16(a0, b2, acc[0][2], 0, 0, 0);
            acc[0][3] = __builtin_amdgcn_mfma_f32_16x16x32_bf16(a0, b3, acc[0][3], 0, 0, 0);
            acc[1][0] = __builtin_amdgcn_mfma_f32_16x16x32_bf16(a1, b0, acc[1][0], 0, 0, 0);
            acc[1][1] = __builtin_amdgcn_mfma_f32_16x16x32_bf16(a1, b1, acc[1][1], 0, 0, 0);
            acc[1][2] = __builtin_amdgcn_mfma_f32_16x16x32_bf16(a1, b2, acc[1][2], 0, 0, 0);
            acc[1][3] = __builtin_amdgcn_mfma_f32_16x16x32_bf16(a1, b3, acc[1][3], 0, 0, 0);
        }
#pragma unroll
        for (int rg = 0; rg < 2; ++rg) {
            int orow = r0 + rg * 16 + lkg * 4;
#pragma unroll
            for (int nt = 0; nt < 4; ++nt) {
                int c = n0 + nt * 16 + lrow;
                float bv = biasB[c];
#pragma unroll
                for (int r = 0; r < 4; ++r) {
                    int grow = orow + r;
                    if (grow >= N_NODES) continue;
                    float v = acc[rg][nt][r] + bv;
                    if (RELU2) v = fmaxf(v, 0.f);
                    if (F32OUT)
                        ((float*)Cout)[(size_t)grow * 256 + c] = v;
                    else
                        ((unsigned short*)Cout)[(size_t)grow * 256 + c] = f2bf(v);
                }
            }
        }
    }
}

// ---------------------------------------------------------------------------
extern "C" void kernel_launch(void* const* d_in, const int* in_sizes, int n_in,
                              void* d_out, int out_size, void* d_ws, size_t ws_size,
                              hipStream_t stream) {
    const float* x   = (const float*)d_in[0];
    const int*   ei  = (const int*)d_in[1];
    const int*   src = ei;
    const int*   dst = ei + N_EDGES;
    const float* W0a = (const float*)d_in[2];
    const float* b0a = (const float*)d_in[3];
    const float* W0b = (const float*)d_in[4];
    const float* b0b = (const float*)d_in[5];
    const float* W1a = (const float*)d_in[6];
    const float* b1a = (const float*)d_in[7];
    const float* W1b = (const float*)d_in[8];
    const float* b1b = (const float*)d_in[9];
    const float* W2a = (const float*)d_in[10];
    const float* b2a = (const float*)d_in[11];
    const float* W2b = (const float*)d_in[12];
    const float* b2b = (const float*)d_in[13];

    char* ws = (char*)d_ws;
    size_t off = 0;
    auto alloc = [&](size_t bytes) {
        void* p = ws + off;
        off += (bytes + 255) & ~(size_t)255;
        return p;
    };
    unsigned short* xb    = (unsigned short*)alloc((size_t)N_NODES * 128 * 2);
    unsigned short* B0    = (unsigned short*)alloc((size_t)N_NODES * 256 * 2);
    unsigned short* B2    = (unsigned short*)alloc((size_t)N_NODES * 256 * 2);
    unsigned short* Wt0a  = (unsigned short*)alloc(256 * 128 * 2);
    unsigned short* Wt0b  = (unsigned short*)alloc(256 * 256 * 2);
    unsigned short* Wt1a  = (unsigned short*)alloc(256 * 256 * 2);
    unsigned short* Wt1b  = (unsigned short*)alloc(256 * 256 * 2);
    unsigned short* Wt2a  = (unsigned short*)alloc(256 * 256 * 2);
    unsigned short* Wt2b  = (unsigned short*)alloc(256 * 256 * 2);
    int*            deg   = (int*)alloc(N_NODES * 4);
    unsigned short* ell   = (unsigned short*)alloc((size_t)N_NODES * ELL_W * 2);
    int*            gCur  = (int*)alloc(NB * 4);
    unsigned*       gBkt  = (unsigned*)alloc((size_t)NB * BCAP * 4);

    dim3 gatherGrid1((N_NODES + 3) / 4, 1);        // C=128: one half
    dim3 gatherGrid2((N_NODES + 3) / 4, 2);        // C=256: two halves
    int mlpBlocks = (N_NODES + 31) / 32;           // 313

    // ---- prep: zero cursors + x->bf16 + weight transpose/convert (1 dispatch)
    WList wl;
    wl.src[0] = W0a; wl.dst[0] = Wt0a; wl.K[0] = 128;
    wl.src[1] = W0b; wl.dst[1] = Wt0b; wl.K[1] = 256;
    wl.src[2] = W1a; wl.dst[2] = Wt1a; wl.K[2] = 256;
    wl.src[3] = W1b; wl.dst[3] = Wt1b; wl.K[3] = 256;
    wl.src[4] = W2a; wl.dst[4] = Wt2a; wl.K[4] = 256;
    wl.src[5] = W2b; wl.dst[5] = Wt2b; wl.K[5] = 256;
    int totalW = 0;
    for (int i = 0; i < 6; ++i) { wl.off[i] = totalW; totalW += wl.K[i] * 256; }
    wl.off[6] = totalW;
    int n4 = N_NODES * 128 / 4;
    int prepTasks = n4 + totalW;
    prep_kernel<<<(prepTasks + 255) / 256, 256, 0, stream>>>(
        (const float4*)x, (ushort4*)xb, n4, wl, totalW, gCur);

    // ---- ELL build ----
    bin_edges<<<(N_EDGES + CHUNK - 1) / CHUNK, 256, 0, stream>>>(src, dst, gCur, gBkt);
    build_ell<<<NB, 256, 0, stream>>>(gBkt, gCur, ell, deg);

    // ---- Layer 0 (C_in = 128) ----
    gather_ell<64><<<gatherGrid1, 256, 0, stream>>>((const unsigned*)xb, ell, deg, (unsigned*)B0);
    mlp_mfma<4, true, false><<<mlpBlocks, 256, 0, stream>>>(B0, Wt0a, b0a, Wt0b, b0b, B2);
    // ---- Layer 1 (C = 256) ----
    gather_ell<128><<<gatherGrid2, 256, 0, stream>>>((const unsigned*)B2, ell, deg, (unsigned*)B0);
    mlp_mfma<8, true, false><<<mlpBlocks, 256, 0, stream>>>(B0, Wt1a, b1a, Wt1b, b1b, B2);
    // ---- Layer 2 (C = 256, final out fp32, no ReLU) ----
    gather_ell<128><<<gatherGrid2, 256, 0, stream>>>((const unsigned*)B2, ell, deg, (unsigned*)B0);
    mlp_mfma<8, false, true><<<mlpBlocks, 256, 0, stream>>>(B0, Wt2a, b2a, Wt2b, b2b, d_out);
}